// Round 13
// baseline (279.851 us; speedup 1.0000x reference)
//
#include <hip/hip_runtime.h>

#define B_    64
#define N_    100
#define D_    32
#define F0    96
#define F1    160
#define F2    192
#define HID   256
#define FOUT  32

typedef unsigned short u16;
typedef unsigned int   u32;
typedef u16   u16x8 __attribute__((ext_vector_type(8)));
typedef u32   u32x2 __attribute__((ext_vector_type(2)));
typedef __bf16 bf16x8 __attribute__((ext_vector_type(8)));
typedef float  fx4   __attribute__((ext_vector_type(4)));

// hardware RNE f32->bf16
__device__ __forceinline__ u16 f2bf(float f) {
    return __builtin_bit_cast(u16, (__bf16)f);
}
// lrelu(v) = max(v, 0.2v): exact (v>0 -> v; v<=0 -> 0.2v)
__device__ __forceinline__ float lrelu(float v) { return fmaxf(v, 0.2f * v); }

__device__ __forceinline__ bf16x8 fragLds(const u16* p) {
    return __builtin_bit_cast(bf16x8, *(const u16x8*)p);
}
__device__ __forceinline__ bf16x8 fragGbl(const u16* __restrict__ p) {
    return __builtin_bit_cast(bf16x8, *(const u16x8*)p);
}
#define MFMA(a, b, c) __builtin_amdgcn_mfma_f32_16x16x32_bf16((a), (b), (c), 0, 0, 0)

// quad-gather: lanes q..q+3 hold bf16 for 4 consecutive u16 of one fragment
// row; quad-lead ((ld&3)==0, even) stores 8B; even-lane pk is valid.
__device__ __forceinline__ u32x2 quadPack(u32 h) {
    u32 h1 = (u32)__shfl_xor((int)h, 1, 64);
    u32 pk = h | (h1 << 16);
    u32 pko = (u32)__shfl_xor((int)pk, 2, 64);
    return (u32x2){pk, pko};
}

// ---- ws layout (bytes) ----
// agg is now f32 (split-j halves combine via atomicAdd); pack moved up.
#define OFF_P     0u
#define OFF_V     2457600u     // 6400*96*4
#define OFF_AGG   4915200u     // f32 [6400*192] = 4,915,200 B
#define OFF_PACK  9830400u     // + 4,915,200
#define PK_W1     0
#define PK_W2     15360
#define PK_N0     46080
#define PK_N1     103424
#define PK_N2     168960
#define PK_TOTAL  177152       // ws end ~10.19 MB

#define PV_BLOCKS 2400
#define PACK_BLOCKS 346

// ============================ prep ============================
__global__ __launch_bounds__(512) void prep_kernel(
    const float* __restrict__ x,
    const float* __restrict__ few0, const float* __restrict__ feb0,
    const float* __restrict__ few1, const float* __restrict__ few2,
    const float* __restrict__ fnw0, const float* __restrict__ fnw1,
    const float* __restrict__ fnw2,
    float* __restrict__ P, float* __restrict__ V, u16* __restrict__ wpack,
    float* __restrict__ aggF)
{
    const int blk = blockIdx.x, tid = threadIdx.x;
    if (blk < PV_BLOCKS) {
        int o = blk * 512 + tid;           // < 6400*192 == agg element count
        aggF[o] = 0.f;                     // zero-init agg accumulator
        int r = o / 192, h = o - r * 192;
        const float* xr = x + r * D_;
        if (h < F0) {
            float acc = feb0[h];
            #pragma unroll
            for (int d = 0; d < D_; ++d) acc = fmaf(xr[d], few0[d * F0 + h], acc);
            P[r * F0 + h] = acc;
        } else {
            int k = h - F0;
            float acc = 0.f;
            #pragma unroll
            for (int d = 0; d < D_; ++d) acc = fmaf(xr[d], few0[(D_ + d) * F0 + k], acc);
            V[r * F0 + k] = acc;
        }
    } else {
        int p = (blk - PV_BLOCKS) * 512 + tid;
        const float* src; int start, Ncols, NT;
        if (p < PK_W2)      { start = PK_W1; src = few1; Ncols = F1;   NT = 10; }
        else if (p < PK_N0) { start = PK_W2; src = few2; Ncols = F2;   NT = 12; }
        else if (p < PK_N1) { start = PK_N0; src = fnw0; Ncols = HID;  NT = 16; }
        else if (p < PK_N2) { start = PK_N1; src = fnw1; Ncols = HID;  NT = 16; }
        else                { start = PK_N2; src = fnw2; Ncols = FOUT; NT = 2;  }
        int local = p - start;
        int j = local & 7, lane = (local >> 3) & 63, rest = local >> 9;
        int nt = rest % NT, kt = rest / NT;
        int n = 16 * nt + (lane & 15);
        int k = 32 * kt + 8 * (lane >> 4) + j;
        wpack[p] = f2bf(src[k * Ncols + n]);
    }
}

// ============================ edge ============================
// SPLIT-J: grid (N_, B_, 2); half h owns mt 0-3 (h=0) or 4-6 (h=1).
// Per half-block LDS: sA0p 4 slices (12.3KB) + sA1p 4 slots (20.5KB) + sP +
// sAggP = 34.7KB -> 4 blocks/CU (wave-cap 32/8=4; LDS 4x34.7=139KB<160).
// Halves combine via atomicAdd f32 (2 commutative contributors ->
// deterministic; node does the single f32->bf16 rounding as before).
// Code sections are r10's verified shape (VGPR 52, zero spill) — only loop
// BOUNDS and the sA1p slot index (mt&3) changed, not the section structure
// (the r5-r9 spill trap was section restructuring, avoided here).
// Swizzle (HW-verified, 0 conflicts): write (rowl*16)^((((rlo>>3)+2*lq)&7)<<4),
// read (ld*16)^(((ld>>3)&7)<<4), within each 1024B kt2-block.
__global__ __launch_bounds__(512, 4) void edge_kernel(
    const float* __restrict__ P, const float* __restrict__ V,
    const u16* __restrict__ W1p, const u16* __restrict__ W2p,
    const float* __restrict__ feb1, const float* __restrict__ feb2,
    float* __restrict__ aggF)
{
    const int i = blockIdx.x, b = blockIdx.y, half = blockIdx.z;
    const int tid = threadIdx.x, ld = tid & 63, wv = tid >> 6;
    const int wn = wv & 3, wm = wv >> 2;
    const int row = b * N_ + i;
    const int mt0 = half ? 4 : 0;
    const int nSl = half ? 3 : 4;            // owned mt slices

    __shared__ __align__(16) u16  sA0p[4 * 3 * 512];   // 12288 B (<=4 slices)
    __shared__ __align__(16) u16  sA1p[4 * 5 * 512];   // 20480 B (swizzled)
    __shared__ __align__(16) float sP[F0];             // 384 B
    __shared__ __align__(16) float sAggP[2 * F2];      // 1536 B [wm][f]

    if (tid < F0) sP[tid] = P[row * F0 + tid];
    __syncthreads();

    // ---- A0 packed build for OWNED slices only: pad rows -> 0 ----
    {
        const float* Vb = V + (size_t)b * N_ * F0;
        const int pairs = nSl * 3;            // 12 (h0) or 9 (h1)
        #pragma unroll
        for (int s = 0; s < 2; ++s) {
            int idx = tid + 512 * s;
            if (idx < pairs * 64) {
                int lane = idx & 63, rest = idx >> 6;
                int kt = rest % 3, mtl = rest / 3;     // local slice
                int k = 32 * kt + 8 * (lane >> 4);
                int m = 16 * (mt0 + mtl) + (lane & 15);
                u16x8 w;
                if (m < N_) {
                    const float* vp = Vb + m * F0 + k;
                    fx4 v0 = *(const fx4*)(vp);
                    fx4 v1 = *(const fx4*)(vp + 4);
                    fx4 p0 = *(const fx4*)(sP + k);
                    fx4 p1 = *(const fx4*)(sP + k + 4);
                    #pragma unroll
                    for (int jj = 0; jj < 4; ++jj) {
                        w[jj]     = f2bf(lrelu(p0[jj] + v0[jj]));
                        w[4 + jj] = f2bf(lrelu(p1[jj] + v1[jj]));
                    }
                } else {
                    w = (u16x8){0, 0, 0, 0, 0, 0, 0, 0};
                }
                *(u16x8*)(sA0p + idx * 8) = w;
            }
        }
    }
    __syncthreads();

    // h0: wm0 -> mt 0,1  wm1 -> mt 2,3 ; h1: wm0 -> mt 4,5  wm1 -> mt 6
    const int mtb = mt0 + 2 * wm;
    const int mte = half ? (wm ? 7 : 6) : (mtb + 2);
    const int c = ld & 15, rlo = (ld >> 4) * 4;
    const int a1off = (ld * 16) ^ (((ld >> 3) & 7) << 4);   // swz read offset

    // ---- edge layer 1: [..x96]@[96x160] -> sA1p slots (swizzled) ----
    {
        const int nCnt = (wn < 2) ? 3 : 2;
        bf16x8 bw[3][3]; float bias[3];
        #pragma unroll
        for (int t = 0; t < 3; ++t) if (t < nCnt) {
            int nt = wn + 4 * t;
            bias[t] = feb1[16 * nt + c];
            #pragma unroll
            for (int kt = 0; kt < 3; ++kt)
                bw[t][kt] = fragGbl(W1p + (size_t)((kt * 10 + nt) * 64 + ld) * 8);
        }
        for (int mt = mtb; mt < mte; ++mt) {
            int mtl = mt - mt0;
            bf16x8 a[3];
            #pragma unroll
            for (int kt = 0; kt < 3; ++kt)
                a[kt] = fragLds(sA0p + ((mtl * 3 + kt) * 64 + ld) * 8);
            fx4 acc[3];
            #pragma unroll
            for (int t = 0; t < 3; ++t) acc[t] = (fx4){0.f, 0.f, 0.f, 0.f};
            #pragma unroll
            for (int kt = 0; kt < 3; ++kt)
                #pragma unroll
                for (int t = 0; t < 3; ++t)
                    if (t < nCnt) acc[t] = MFMA(a[kt], bw[t][kt], acc[t]);
            // swizzled quad-packed repack (HW-verified)
            #pragma unroll
            for (int t = 0; t < 3; ++t) if (t < nCnt) {
                int nt = wn + 4 * t;
                int f = 16 * nt + c;
                int lq = (f >> 3) & 3;
                int S  = (((rlo >> 3) + 2 * lq) & 7) << 4;
                char* base = (char*)sA1p + ((mt & 3) * 5 + (nt >> 1)) * 1024 + (c & 4) * 2;
                #pragma unroll
                for (int r = 0; r < 4; ++r) {
                    u32 h = (u32)f2bf(lrelu(acc[t][r] + bias[t]));
                    u32x2 two = quadPack(h);
                    int rowl = rlo + 16 * lq + r;
                    if ((ld & 3) == 0)
                        *(u32x2*)(base + ((rowl * 16) ^ S)) = two;
                }
            }
        }
    }
    __syncthreads();

    // ---- edge layer 2 + fused partial aggregation over owned j ----
    {
        bf16x8 bw[3][5]; float bias[3];
        float aggp[3] = {0.f, 0.f, 0.f};
        #pragma unroll
        for (int t = 0; t < 3; ++t) {
            int nt = wn + 4 * t;
            bias[t] = feb2[16 * nt + c];
            #pragma unroll
            for (int kt = 0; kt < 5; ++kt)
                bw[t][kt] = fragGbl(W2p + (size_t)((kt * 12 + nt) * 64 + ld) * 8);
        }
        for (int mt = mtb; mt < mte; ++mt) {
            bf16x8 a[5];
            const char* rb = (const char*)sA1p + (mt & 3) * 5120 + a1off;
            #pragma unroll
            for (int kt = 0; kt < 5; ++kt)
                a[kt] = fragLds((const u16*)(rb + kt * 1024));
            fx4 acc[3];
            #pragma unroll
            for (int t = 0; t < 3; ++t) acc[t] = (fx4){0.f, 0.f, 0.f, 0.f};
            #pragma unroll
            for (int kt = 0; kt < 5; ++kt)
                #pragma unroll
                for (int t = 0; t < 3; ++t)
                    acc[t] = MFMA(a[kt], bw[t][kt], acc[t]);
            // rows m = 16*mt + rlo + r ; mask out pad rows (>=100)
            bool ok = (mt < 6) || (rlo == 0);
            if (ok) {
                #pragma unroll
                for (int t = 0; t < 3; ++t)
                    #pragma unroll
                    for (int r = 0; r < 4; ++r)
                        aggp[t] += lrelu(acc[t][r] + bias[t]);
            }
        }
        #pragma unroll
        for (int t = 0; t < 3; ++t) {
            aggp[t] += __shfl_xor(aggp[t], 16, 64);
            aggp[t] += __shfl_xor(aggp[t], 32, 64);
        }
        if (ld < 16) {
            #pragma unroll
            for (int t = 0; t < 3; ++t)
                sAggP[wm * F2 + 16 * (wn + 4 * t) + ld] = aggp[t];
        }
    }
    __syncthreads();

    if (tid < F2) {
        float v = sAggP[tid] + sAggP[F2 + tid];
        atomicAdd(aggF + (size_t)row * F2 + tid, v);
    }
}

// ============================ node ============================
__global__ __launch_bounds__(512, 4) void node_kernel(
    const float* __restrict__ aggF, const float* __restrict__ x,
    const u16* __restrict__ n0p, const u16* __restrict__ n1p,
    const u16* __restrict__ n2p,
    const float* __restrict__ fnb0, const float* __restrict__ fnb1,
    const float* __restrict__ fnb2,
    float* __restrict__ out)
{
    const int blk = blockIdx.x;
    const int tid = threadIdx.x, ld = tid & 63, wv = tid >> 6;
    const int wn = wv & 3, mt = wv >> 2;
    const int c = ld & 15, rlo = (ld >> 4) * 4;
    const int c0 = c & ~3;

    __shared__ __align__(16) u16 sH0p[2 * 7 * 512];
    __shared__ __align__(16) u16 sH1p[2 * 8 * 512];
    __shared__ __align__(16) u16 sH2p[2 * 8 * 512];

    #pragma unroll
    for (int s = 0; s < 2; ++s) {
        int idx = tid + 512 * s;
        if (idx < 896) {
            int lane = idx & 63, rest = idx >> 6;
            int kt = rest % 7, mtt = rest / 7;
            int k = 32 * kt + 8 * (lane >> 4);
            int m = 16 * mtt + (lane & 15);
            int g = 32 * blk + m;
            u16x8 w;
            if (k < F2) {
                const float* ap = aggF + (size_t)g * F2 + k;
                fx4 a0 = *(const fx4*)ap;
                fx4 a1 = *(const fx4*)(ap + 4);
                #pragma unroll
                for (int jj = 0; jj < 4; ++jj) {
                    w[jj] = f2bf(a0[jj]); w[4 + jj] = f2bf(a1[jj]);
                }
            } else {
                const float* xp = x + (size_t)g * D_ + (k - F2);
                fx4 v0 = *(const fx4*)xp;
                fx4 v1 = *(const fx4*)(xp + 4);
                #pragma unroll
                for (int jj = 0; jj < 4; ++jj) {
                    w[jj] = f2bf(v0[jj]); w[4 + jj] = f2bf(v1[jj]);
                }
            }
            *(u16x8*)(sH0p + idx * 8) = w;
        }
    }
    __syncthreads();

    {
        fx4 acc[4];
        #pragma unroll
        for (int t = 0; t < 4; ++t) acc[t] = (fx4){0.f, 0.f, 0.f, 0.f};
        for (int kt = 0; kt < 7; ++kt) {
            bf16x8 a = fragLds(sH0p + ((mt * 7 + kt) * 64 + ld) * 8);
            #pragma unroll
            for (int t = 0; t < 4; ++t) {
                bf16x8 bw = fragGbl(n0p + (size_t)((kt * 16 + wn + 4 * t) * 64 + ld) * 8);
                acc[t] = MFMA(a, bw, acc[t]);
            }
        }
        #pragma unroll
        for (int t = 0; t < 4; ++t) {
            int f = 16 * (wn + 4 * t) + c;
            float bias = fnb0[f];
            int kt2 = f >> 5, lq = (f >> 3) & 3;
            u16* basep = sH1p + ((mt * 8 + kt2) * 64 + rlo + 16 * lq) * 8 + (c0 & 7);
            #pragma unroll
            for (int r = 0; r < 4; ++r) {
                u32 h = (u32)f2bf(lrelu(acc[t][r] + bias));
                u32x2 two = quadPack(h);
                if ((ld & 3) == 0)
                    *(u32x2*)(basep + r * 8) = two;
            }
        }
    }
    __syncthreads();

    {
        fx4 acc[4];
        #pragma unroll
        for (int t = 0; t < 4; ++t) acc[t] = (fx4){0.f, 0.f, 0.f, 0.f};
        for (int kt = 0; kt < 8; ++kt) {
            bf16x8 a = fragLds(sH1p + ((mt * 8 + kt) * 64 + ld) * 8);
            #pragma unroll
            for (int t = 0; t < 4; ++t) {
                bf16x8 bw = fragGbl(n1p + (size_t)((kt * 16 + wn + 4 * t) * 64 + ld) * 8);
                acc[t] = MFMA(a, bw, acc[t]);
            }
        }
        #pragma unroll
        for (int t = 0; t < 4; ++t) {
            int f = 16 * (wn + 4 * t) + c;
            float bias = fnb1[f];
            int kt2 = f >> 5, lq = (f >> 3) & 3;
            u16* basep = sH2p + ((mt * 8 + kt2) * 64 + rlo + 16 * lq) * 8 + (c0 & 7);
            #pragma unroll
            for (int r = 0; r < 4; ++r) {
                u32 h = (u32)f2bf(lrelu(acc[t][r] + bias));
                u32x2 two = quadPack(h);
                if ((ld & 3) == 0)
                    *(u32x2*)(basep + r * 8) = two;
            }
        }
    }
    __syncthreads();

    if (wv < 4) {
        int mt2 = wv >> 1, nt = wv & 1;
        fx4 acc = (fx4){0.f, 0.f, 0.f, 0.f};
        for (int kt = 0; kt < 8; ++kt) {
            bf16x8 a = fragLds(sH2p + ((mt2 * 8 + kt) * 64 + ld) * 8);
            bf16x8 bw = fragGbl(n2p + (size_t)((kt * 2 + nt) * 64 + ld) * 8);
            acc = MFMA(a, bw, acc);
        }
        int f = 16 * nt + c;
        float bias = fnb2[f];
        #pragma unroll
        for (int r = 0; r < 4; ++r) {
            int g = 32 * blk + 16 * mt2 + rlo + r;
            out[(size_t)g * FOUT + f] = acc[r] + bias;
        }
    }
}

extern "C" void kernel_launch(void* const* d_in, const int* in_sizes, int n_in,
                              void* d_out, int out_size, void* d_ws, size_t ws_size,
                              hipStream_t stream) {
    const float* x    = (const float*)d_in[0];
    const float* few0 = (const float*)d_in[1];
    const float* feb0 = (const float*)d_in[2];
    const float* few1 = (const float*)d_in[3];
    const float* feb1 = (const float*)d_in[4];
    const float* few2 = (const float*)d_in[5];
    const float* feb2 = (const float*)d_in[6];
    const float* fnw0 = (const float*)d_in[7];
    const float* fnb0 = (const float*)d_in[8];
    const float* fnw1 = (const float*)d_in[9];
    const float* fnb1 = (const float*)d_in[10];
    const float* fnw2 = (const float*)d_in[11];
    const float* fnb2 = (const float*)d_in[12];

    char* w = (char*)d_ws;
    float* P    = (float*)(w + OFF_P);
    float* V    = (float*)(w + OFF_V);
    float* aggF = (float*)(w + OFF_AGG);
    u16*   pack = (u16*)(w + OFF_PACK);

    prep_kernel<<<PV_BLOCKS + PACK_BLOCKS, 512, 0, stream>>>(
        x, few0, feb0, few1, few2, fnw0, fnw1, fnw2, P, V, pack, aggF);

    edge_kernel<<<dim3(N_, B_, 2), 512, 0, stream>>>(
        P, V, pack + PK_W1, pack + PK_W2, feb1, feb2, aggF);

    node_kernel<<<200, 512, 0, stream>>>(
        aggF, x, pack + PK_N0, pack + PK_N1, pack + PK_N2,
        fnb0, fnb1, fnb2, (float*)d_out);
}

// Round 14
// 246.303 us; speedup vs baseline: 1.1362x; 1.1362x over previous
//
#include <hip/hip_runtime.h>

#define B_    64
#define N_    100
#define D_    32
#define F0    96
#define F1    160
#define F2    192
#define HID   256
#define FOUT  32

typedef unsigned short u16;
typedef unsigned int   u32;
typedef u16   u16x8 __attribute__((ext_vector_type(8)));
typedef u32   u32x2 __attribute__((ext_vector_type(2)));
typedef __bf16 bf16x8 __attribute__((ext_vector_type(8)));
typedef float  fx4   __attribute__((ext_vector_type(4)));

// hardware RNE f32->bf16
__device__ __forceinline__ u16 f2bf(float f) {
    return __builtin_bit_cast(u16, (__bf16)f);
}
// lrelu(v) = max(v, 0.2v): exact (v>0 -> v; v<=0 -> 0.2v)
__device__ __forceinline__ float lrelu(float v) { return fmaxf(v, 0.2f * v); }

__device__ __forceinline__ bf16x8 fragLds(const u16* p) {
    return __builtin_bit_cast(bf16x8, *(const u16x8*)p);
}
__device__ __forceinline__ bf16x8 fragGbl(const u16* __restrict__ p) {
    return __builtin_bit_cast(bf16x8, *(const u16x8*)p);
}
#define MFMA(a, b, c) __builtin_amdgcn_mfma_f32_16x16x32_bf16((a), (b), (c), 0, 0, 0)

// quad-gather: lanes q..q+3 hold bf16 for 4 consecutive u16 of one fragment
// row; quad-lead ((ld&3)==0, even) stores 8B; even-lane pk is valid.
__device__ __forceinline__ u32x2 quadPack(u32 h) {
    u32 h1 = (u32)__shfl_xor((int)h, 1, 64);
    u32 pk = h | (h1 << 16);
    u32 pko = (u32)__shfl_xor((int)pk, 2, 64);
    return (u32x2){pk, pko};
}

// ---- ws layout (bytes) ---- (r10 layout: agg is bf16/u16)
#define OFF_P     0u
#define OFF_V     2457600u
#define OFF_AGG   4915200u
#define OFF_PACK  7372800u
#define PK_W1     0
#define PK_W2     15360
#define PK_N0     46080
#define PK_N1     103424
#define PK_N2     168960
#define PK_TOTAL  177152

#define PV_BLOCKS 2400
#define PACK_BLOCKS 346

// ============================ prep ============================
__global__ __launch_bounds__(512) void prep_kernel(
    const float* __restrict__ x,
    const float* __restrict__ few0, const float* __restrict__ feb0,
    const float* __restrict__ few1, const float* __restrict__ few2,
    const float* __restrict__ fnw0, const float* __restrict__ fnw1,
    const float* __restrict__ fnw2,
    float* __restrict__ P, float* __restrict__ V, u16* __restrict__ wpack)
{
    const int blk = blockIdx.x, tid = threadIdx.x;
    if (blk < PV_BLOCKS) {
        int o = blk * 512 + tid;
        int r = o / 192, h = o - r * 192;
        const float* xr = x + r * D_;
        if (h < F0) {
            float acc = feb0[h];
            #pragma unroll
            for (int d = 0; d < D_; ++d) acc = fmaf(xr[d], few0[d * F0 + h], acc);
            P[r * F0 + h] = acc;
        } else {
            int k = h - F0;
            float acc = 0.f;
            #pragma unroll
            for (int d = 0; d < D_; ++d) acc = fmaf(xr[d], few0[(D_ + d) * F0 + k], acc);
            V[r * F0 + k] = acc;
        }
    } else {
        int p = (blk - PV_BLOCKS) * 512 + tid;
        const float* src; int start, Ncols, NT;
        if (p < PK_W2)      { start = PK_W1; src = few1; Ncols = F1;   NT = 10; }
        else if (p < PK_N0) { start = PK_W2; src = few2; Ncols = F2;   NT = 12; }
        else if (p < PK_N1) { start = PK_N0; src = fnw0; Ncols = HID;  NT = 16; }
        else if (p < PK_N2) { start = PK_N1; src = fnw1; Ncols = HID;  NT = 16; }
        else                { start = PK_N2; src = fnw2; Ncols = FOUT; NT = 2;  }
        int local = p - start;
        int j = local & 7, lane = (local >> 3) & 63, rest = local >> 9;
        int nt = rest % NT, kt = rest / NT;
        int n = 16 * nt + (lane & 15);
        int k = 32 * kt + 8 * (lane >> 4) + j;
        wpack[p] = f2bf(src[k * Ncols + n]);
    }
}

// ============================ edge ============================
// one block per (b,i); 8 waves: wm = wv>>2, wn = wv&3.
// Base = HW-verified r10 kernel (245.8us total: edge 161.5us, VGPR 52, zero
// spill, swizzled sA1p, 0 bank conflicts). Occupancy is PINNED ~43% on this
// chip regardless of LDS (59/44/38/35KB all gave 43%) — unified VGPR+AGPR
// total caps waves/SIMD; do NOT chase occupancy (r5/r7/r8/r12/r13 all lost).
// THIS ROUND's only edge change: sP LDS stage removed — A0 build reads the
// 384B P row directly from global (L1-broadcast). Deletes the single-wave
// load + the block's first barrier. Bit-exact.
// Swizzle (HW-verified, 0 conflicts): write (rowl*16)^((((rlo>>3)+2*lq)&7)<<4),
// read (ld*16)^(((ld>>3)&7)<<4), within each 1024B kt2-block.
__global__ __launch_bounds__(512, 4) void edge_kernel(
    const float* __restrict__ P, const float* __restrict__ V,
    const u16* __restrict__ W1p, const u16* __restrict__ W2p,
    const float* __restrict__ feb1, const float* __restrict__ feb2,
    u16* __restrict__ agg)
{
    const int i = blockIdx.x, b = blockIdx.y;
    const int tid = threadIdx.x, ld = tid & 63, wv = tid >> 6;
    const int wn = wv & 3, wm = wv >> 2;
    const int row = b * N_ + i;

    __shared__ __align__(16) u16  sA0p[7 * 3 * 512];   // 21504 B
    __shared__ __align__(16) u16  sA1p[7 * 5 * 512];   // 35840 B (swizzled)
    __shared__ __align__(16) float sAggP[2 * F2];      // [wm][f]

    // ---- A0 packed build (vector, verified): pad rows -> 0 ----
    {
        const float* Vb = V + (size_t)b * N_ * F0;
        const float* Pr = P + (size_t)row * F0;
        #pragma unroll
        for (int s = 0; s < 3; ++s) {
            int idx = tid + 512 * s;                   // < 1344 = 21*64
            if (idx < 1344) {
                int lane = idx & 63, rest = idx >> 6;  // rest < 21
                int kt = rest % 3, mt = rest / 3;
                int k = 32 * kt + 8 * (lane >> 4);
                int m = 16 * mt + (lane & 15);
                u16x8 w;
                if (m < N_) {
                    const float* vp = Vb + m * F0 + k;
                    fx4 v0 = *(const fx4*)(vp);
                    fx4 v1 = *(const fx4*)(vp + 4);
                    fx4 p0 = *(const fx4*)(Pr + k);
                    fx4 p1 = *(const fx4*)(Pr + k + 4);
                    #pragma unroll
                    for (int jj = 0; jj < 4; ++jj) {
                        w[jj]     = f2bf(lrelu(p0[jj] + v0[jj]));
                        w[4 + jj] = f2bf(lrelu(p1[jj] + v1[jj]));
                    }
                } else {
                    w = (u16x8){0, 0, 0, 0, 0, 0, 0, 0};
                }
                *(u16x8*)(sA0p + idx * 8) = w;
            }
        }
    }
    __syncthreads();

    const int mtB = wm ? 4 : 0, mtE = wm ? 7 : 4;
    const int c = ld & 15, rlo = (ld >> 4) * 4;
    const int a1off = (ld * 16) ^ (((ld >> 3) & 7) << 4);   // swz read offset

    // ---- edge layer 1: [112x96] @ [96x160] -> sA1p (swizzled packed-A) ----
    {
        const int nCnt = (wn < 2) ? 3 : 2;
        bf16x8 bw[3][3]; float bias[3];
        #pragma unroll
        for (int t = 0; t < 3; ++t) if (t < nCnt) {
            int nt = wn + 4 * t;
            bias[t] = feb1[16 * nt + c];
            #pragma unroll
            for (int kt = 0; kt < 3; ++kt)
                bw[t][kt] = fragGbl(W1p + (size_t)((kt * 10 + nt) * 64 + ld) * 8);
        }
        for (int mt = mtB; mt < mtE; ++mt) {
            bf16x8 a[3];
            #pragma unroll
            for (int kt = 0; kt < 3; ++kt)
                a[kt] = fragLds(sA0p + ((mt * 3 + kt) * 64 + ld) * 8);
            fx4 acc[3];
            #pragma unroll
            for (int t = 0; t < 3; ++t) acc[t] = (fx4){0.f, 0.f, 0.f, 0.f};
            #pragma unroll
            for (int kt = 0; kt < 3; ++kt)
                #pragma unroll
                for (int t = 0; t < 3; ++t)
                    if (t < nCnt) acc[t] = MFMA(a[kt], bw[t][kt], acc[t]);
            // swizzled quad-packed repack (HW-verified)
            #pragma unroll
            for (int t = 0; t < 3; ++t) if (t < nCnt) {
                int nt = wn + 4 * t;
                int f = 16 * nt + c;
                int lq = (f >> 3) & 3;
                int S  = (((rlo >> 3) + 2 * lq) & 7) << 4;
                char* base = (char*)sA1p + (mt * 5 + (nt >> 1)) * 1024 + (c & 4) * 2;
                #pragma unroll
                for (int r = 0; r < 4; ++r) {
                    u32 h = (u32)f2bf(lrelu(acc[t][r] + bias[t]));
                    u32x2 two = quadPack(h);
                    int rowl = rlo + 16 * lq + r;
                    if ((ld & 3) == 0)
                        *(u32x2*)(base + ((rowl * 16) ^ S)) = two;
                }
            }
        }
    }
    __syncthreads();

    // ---- edge layer 2 + fused aggregation over j (unchanged, verified) ----
    {
        bf16x8 bw[3][5]; float bias[3];
        float aggp[3] = {0.f, 0.f, 0.f};
        #pragma unroll
        for (int t = 0; t < 3; ++t) {
            int nt = wn + 4 * t;
            bias[t] = feb2[16 * nt + c];
            #pragma unroll
            for (int kt = 0; kt < 5; ++kt)
                bw[t][kt] = fragGbl(W2p + (size_t)((kt * 12 + nt) * 64 + ld) * 8);
        }
        for (int mt = mtB; mt < mtE; ++mt) {
            bf16x8 a[5];
            const char* rb = (const char*)sA1p + mt * 5120 + a1off;
            #pragma unroll
            for (int kt = 0; kt < 5; ++kt)
                a[kt] = fragLds((const u16*)(rb + kt * 1024));
            fx4 acc[3];
            #pragma unroll
            for (int t = 0; t < 3; ++t) acc[t] = (fx4){0.f, 0.f, 0.f, 0.f};
            #pragma unroll
            for (int kt = 0; kt < 5; ++kt)
                #pragma unroll
                for (int t = 0; t < 3; ++t)
                    acc[t] = MFMA(a[kt], bw[t][kt], acc[t]);
            // rows m = 16*mt + rlo + r ; mask out pad rows (>=100)
            bool ok = (mt < 6) || (rlo == 0);
            if (ok) {
                #pragma unroll
                for (int t = 0; t < 3; ++t)
                    #pragma unroll
                    for (int r = 0; r < 4; ++r)
                        aggp[t] += lrelu(acc[t][r] + bias[t]);
            }
        }
        #pragma unroll
        for (int t = 0; t < 3; ++t) {
            aggp[t] += __shfl_xor(aggp[t], 16, 64);
            aggp[t] += __shfl_xor(aggp[t], 32, 64);
        }
        if (ld < 16) {
            #pragma unroll
            for (int t = 0; t < 3; ++t)
                sAggP[wm * F2 + 16 * (wn + 4 * t) + ld] = aggp[t];
        }
    }
    __syncthreads();

    if (tid < F2) {
        float v = sAggP[tid] + sAggP[F2 + tid];
        agg[(size_t)row * F2 + tid] = f2bf(v);
    }
}

// ============================ node ============================
// RE-GRIDDED: 400 blocks x 16 rows (was 200x32 -> 0.78 blocks/CU underfill).
// 8 waves; waves own nt = wv and wv+8 (16 nt x 16 rows per layer).
// LDS 23.5KB. Layer-2 (N=32) on 2 waves. Same packed-weight layout as r10.
__global__ __launch_bounds__(512, 4) void node_kernel(
    const u16* __restrict__ agg, const float* __restrict__ x,
    const u16* __restrict__ n0p, const u16* __restrict__ n1p,
    const u16* __restrict__ n2p,
    const float* __restrict__ fnb0, const float* __restrict__ fnb1,
    const float* __restrict__ fnb2,
    float* __restrict__ out)
{
    const int blk = blockIdx.x;                 // 0..399, 16 rows each
    const int tid = threadIdx.x, ld = tid & 63, wv = tid >> 6;
    const int c = ld & 15, rlo = (ld >> 4) * 4;
    const int c0 = c & ~3;

    __shared__ __align__(16) u16 sH0p[7 * 512];   // 7168 B  [7kt][64][8]
    __shared__ __align__(16) u16 sH1p[8 * 512];   // 8192 B  [8kt2][64][8]
    __shared__ __align__(16) u16 sH2p[8 * 512];   // 8192 B

    // ---- stage H0 = [agg | x] packed-A for 16 rows (448 active threads) ----
    if (tid < 448) {
        int lane = tid & 63, kt = tid >> 6;       // kt < 7
        int k = 32 * kt + 8 * (lane >> 4);
        int m = lane & 15;
        int g = 16 * blk + m;
        u16x8 w;
        if (k < F2) {
            w = *(const u16x8*)(agg + (size_t)g * F2 + k);
        } else {
            const float* xp = x + (size_t)g * D_ + (k - F2);
            fx4 v0 = *(const fx4*)xp;
            fx4 v1 = *(const fx4*)(xp + 4);
            #pragma unroll
            for (int jj = 0; jj < 4; ++jj) {
                w[jj] = f2bf(v0[jj]); w[4 + jj] = f2bf(v1[jj]);
            }
        }
        *(u16x8*)(sH0p + tid * 8) = w;
    }
    __syncthreads();

    // ---- node layer 0: K=224 (7 kt), N=256 (nt = wv, wv+8), lrelu ----
    {
        fx4 acc[2];
        #pragma unroll
        for (int t = 0; t < 2; ++t) acc[t] = (fx4){0.f, 0.f, 0.f, 0.f};
        for (int kt = 0; kt < 7; ++kt) {
            bf16x8 a = fragLds(sH0p + (kt * 64 + ld) * 8);
            #pragma unroll
            for (int t = 0; t < 2; ++t) {
                int nt = wv + 8 * t;
                bf16x8 bw = fragGbl(n0p + (size_t)((kt * 16 + nt) * 64 + ld) * 8);
                acc[t] = MFMA(a, bw, acc[t]);
            }
        }
        #pragma unroll
        for (int t = 0; t < 2; ++t) {
            int f = 16 * (wv + 8 * t) + c;
            float bias = fnb0[f];
            int kt2 = f >> 5, lq = (f >> 3) & 3;
            u16* basep = sH1p + (kt2 * 64 + rlo + 16 * lq) * 8 + (c0 & 7);
            #pragma unroll
            for (int r = 0; r < 4; ++r) {
                u32 h = (u32)f2bf(lrelu(acc[t][r] + bias));
                u32x2 two = quadPack(h);
                if ((ld & 3) == 0)
                    *(u32x2*)(basep + r * 8) = two;
            }
        }
    }
    __syncthreads();

    // ---- node layer 1: K=256 (8 kt), N=256, lrelu ----
    {
        fx4 acc[2];
        #pragma unroll
        for (int t = 0; t < 2; ++t) acc[t] = (fx4){0.f, 0.f, 0.f, 0.f};
        for (int kt = 0; kt < 8; ++kt) {
            bf16x8 a = fragLds(sH1p + (kt * 64 + ld) * 8);
            #pragma unroll
            for (int t = 0; t < 2; ++t) {
                int nt = wv + 8 * t;
                bf16x8 bw = fragGbl(n1p + (size_t)((kt * 16 + nt) * 64 + ld) * 8);
                acc[t] = MFMA(a, bw, acc[t]);
            }
        }
        #pragma unroll
        for (int t = 0; t < 2; ++t) {
            int f = 16 * (wv + 8 * t) + c;
            float bias = fnb1[f];
            int kt2 = f >> 5, lq = (f >> 3) & 3;
            u16* basep = sH2p + (kt2 * 64 + rlo + 16 * lq) * 8 + (c0 & 7);
            #pragma unroll
            for (int r = 0; r < 4; ++r) {
                u32 h = (u32)f2bf(lrelu(acc[t][r] + bias));
                u32x2 two = quadPack(h);
                if ((ld & 3) == 0)
                    *(u32x2*)(basep + r * 8) = two;
            }
        }
    }
    __syncthreads();

    // ---- node layer 2: K=256 (8 kt), N=32 (2 nt), linear -> out ----
    if (wv < 2) {
        int nt = wv;
        fx4 acc = (fx4){0.f, 0.f, 0.f, 0.f};
        for (int kt = 0; kt < 8; ++kt) {
            bf16x8 a = fragLds(sH2p + (kt * 64 + ld) * 8);
            bf16x8 bw = fragGbl(n2p + (size_t)((kt * 2 + nt) * 64 + ld) * 8);
            acc = MFMA(a, bw, acc);
        }
        int f = 16 * nt + c;
        float bias = fnb2[f];
        #pragma unroll
        for (int r = 0; r < 4; ++r) {
            int g = 16 * blk + rlo + r;
            out[(size_t)g * FOUT + f] = acc[r] + bias;
        }
    }
}

extern "C" void kernel_launch(void* const* d_in, const int* in_sizes, int n_in,
                              void* d_out, int out_size, void* d_ws, size_t ws_size,
                              hipStream_t stream) {
    const float* x    = (const float*)d_in[0];
    const float* few0 = (const float*)d_in[1];
    const float* feb0 = (const float*)d_in[2];
    const float* few1 = (const float*)d_in[3];
    const float* feb1 = (const float*)d_in[4];
    const float* few2 = (const float*)d_in[5];
    const float* feb2 = (const float*)d_in[6];
    const float* fnw0 = (const float*)d_in[7];
    const float* fnb0 = (const float*)d_in[8];
    const float* fnw1 = (const float*)d_in[9];
    const float* fnb1 = (const float*)d_in[10];
    const float* fnw2 = (const float*)d_in[11];
    const float* fnb2 = (const float*)d_in[12];

    char* w = (char*)d_ws;
    float* P    = (float*)(w + OFF_P);
    float* V    = (float*)(w + OFF_V);
    u16*   aggb = (u16*)(w + OFF_AGG);
    u16*   pack = (u16*)(w + OFF_PACK);

    prep_kernel<<<PV_BLOCKS + PACK_BLOCKS, 512, 0, stream>>>(
        x, few0, feb0, few1, few2, fnw0, fnw1, fnw2, P, V, pack);

    edge_kernel<<<dim3(N_, B_), 512, 0, stream>>>(
        P, V, pack + PK_W1, pack + PK_W2, feb1, feb2, aggb);

    node_kernel<<<400, 512, 0, stream>>>(
        aggb, x, pack + PK_N0, pack + PK_N1, pack + PK_N2,
        fnb0, fnb1, fnb2, (float*)d_out);
}

// Round 15
// 244.910 us; speedup vs baseline: 1.1427x; 1.0057x over previous
//
#include <hip/hip_runtime.h>

#define B_    64
#define N_    100
#define D_    32
#define F0    96
#define F1    160
#define F2    192
#define HID   256
#define FOUT  32

typedef unsigned short u16;
typedef unsigned int   u32;
typedef u16   u16x8 __attribute__((ext_vector_type(8)));
typedef u32   u32x2 __attribute__((ext_vector_type(2)));
typedef __bf16 bf16x8 __attribute__((ext_vector_type(8)));
typedef float  fx4   __attribute__((ext_vector_type(4)));

// hardware RNE f32->bf16
__device__ __forceinline__ u16 f2bf(float f) {
    return __builtin_bit_cast(u16, (__bf16)f);
}
// lrelu(v) = max(v, 0.2v): exact (v>0 -> v; v<=0 -> 0.2v)
__device__ __forceinline__ float lrelu(float v) { return fmaxf(v, 0.2f * v); }

__device__ __forceinline__ bf16x8 fragLds(const u16* p) {
    return __builtin_bit_cast(bf16x8, *(const u16x8*)p);
}
__device__ __forceinline__ bf16x8 fragGbl(const u16* __restrict__ p) {
    return __builtin_bit_cast(bf16x8, *(const u16x8*)p);
}
#define MFMA(a, b, c) __builtin_amdgcn_mfma_f32_16x16x32_bf16((a), (b), (c), 0, 0, 0)

// quad-gather: lanes q..q+3 hold bf16 for 4 consecutive u16 of one fragment
// row; quad-lead ((ld&3)==0, even) stores 8B; even-lane pk is valid.
__device__ __forceinline__ u32x2 quadPack(u32 h) {
    u32 h1 = (u32)__shfl_xor((int)h, 1, 64);
    u32 pk = h | (h1 << 16);
    u32 pko = (u32)__shfl_xor((int)pk, 2, 64);
    return (u32x2){pk, pko};
}

// ---- ws layout (bytes) ----
#define OFF_P     0u
#define OFF_V     2457600u
#define OFF_AGG   4915200u
#define OFF_PACK  7372800u
#define PK_W1     0
#define PK_W2     15360
#define PK_N0     46080
#define PK_N1     103424
#define PK_N2     168960
#define PK_TOTAL  177152

#define PV_BLOCKS 2400
#define PACK_BLOCKS 346

// ============================ prep ============================
__global__ __launch_bounds__(512) void prep_kernel(
    const float* __restrict__ x,
    const float* __restrict__ few0, const float* __restrict__ feb0,
    const float* __restrict__ few1, const float* __restrict__ few2,
    const float* __restrict__ fnw0, const float* __restrict__ fnw1,
    const float* __restrict__ fnw2,
    float* __restrict__ P, float* __restrict__ V, u16* __restrict__ wpack)
{
    const int blk = blockIdx.x, tid = threadIdx.x;
    if (blk < PV_BLOCKS) {
        int o = blk * 512 + tid;
        int r = o / 192, h = o - r * 192;
        const float* xr = x + r * D_;
        if (h < F0) {
            float acc = feb0[h];
            #pragma unroll
            for (int d = 0; d < D_; ++d) acc = fmaf(xr[d], few0[d * F0 + h], acc);
            P[r * F0 + h] = acc;
        } else {
            int k = h - F0;
            float acc = 0.f;
            #pragma unroll
            for (int d = 0; d < D_; ++d) acc = fmaf(xr[d], few0[(D_ + d) * F0 + k], acc);
            V[r * F0 + k] = acc;
        }
    } else {
        int p = (blk - PV_BLOCKS) * 512 + tid;
        const float* src; int start, Ncols, NT;
        if (p < PK_W2)      { start = PK_W1; src = few1; Ncols = F1;   NT = 10; }
        else if (p < PK_N0) { start = PK_W2; src = few2; Ncols = F2;   NT = 12; }
        else if (p < PK_N1) { start = PK_N0; src = fnw0; Ncols = HID;  NT = 16; }
        else if (p < PK_N2) { start = PK_N1; src = fnw1; Ncols = HID;  NT = 16; }
        else                { start = PK_N2; src = fnw2; Ncols = FOUT; NT = 2;  }
        int local = p - start;
        int j = local & 7, lane = (local >> 3) & 63, rest = local >> 9;
        int nt = rest % NT, kt = rest / NT;
        int n = 16 * nt + (lane & 15);
        int k = 32 * kt + 8 * (lane >> 4) + j;
        wpack[p] = f2bf(src[k * Ncols + n]);
    }
}

// ============================ edge ============================
// EXACT r10 kernel (HW-verified 161.5us: VGPR 52, zero spill, swizzled sA1p,
// 0 bank conflicts). sP LDS stage KEPT (r14 A/B: removing it cost +4.7us).
// Occupancy is PINNED ~43% on this chip regardless of LDS (59/44/38/35KB all
// gave 43%) — unified VGPR+AGPR total caps waves/SIMD; do NOT chase occupancy
// (r5/r7/r8/r12/r13 all lost). L1 flat rebalance also lost (r11: broke
// 3-chain acc ILP). In-register A0 lost (r12: +VALU on critical path).
// Swizzle (HW-verified, 0 conflicts): write (rowl*16)^((((rlo>>3)+2*lq)&7)<<4),
// read (ld*16)^(((ld>>3)&7)<<4), within each 1024B kt2-block.
__global__ __launch_bounds__(512, 4) void edge_kernel(
    const float* __restrict__ P, const float* __restrict__ V,
    const u16* __restrict__ W1p, const u16* __restrict__ W2p,
    const float* __restrict__ feb1, const float* __restrict__ feb2,
    u16* __restrict__ agg)
{
    const int i = blockIdx.x, b = blockIdx.y;
    const int tid = threadIdx.x, ld = tid & 63, wv = tid >> 6;
    const int wn = wv & 3, wm = wv >> 2;
    const int row = b * N_ + i;

    __shared__ __align__(16) u16  sA0p[7 * 3 * 512];   // 21504 B
    __shared__ __align__(16) u16  sA1p[7 * 5 * 512];   // 35840 B (swizzled)
    __shared__ __align__(16) float sP[F0];
    __shared__ __align__(16) float sAggP[2 * F2];      // [wm][f]

    if (tid < F0) sP[tid] = P[row * F0 + tid];
    __syncthreads();

    // ---- A0 packed build (vector, verified): pad rows -> 0 ----
    {
        const float* Vb = V + (size_t)b * N_ * F0;
        #pragma unroll
        for (int s = 0; s < 3; ++s) {
            int idx = tid + 512 * s;                   // < 1344 = 21*64
            if (idx < 1344) {
                int lane = idx & 63, rest = idx >> 6;  // rest < 21
                int kt = rest % 3, mt = rest / 3;
                int k = 32 * kt + 8 * (lane >> 4);
                int m = 16 * mt + (lane & 15);
                u16x8 w;
                if (m < N_) {
                    const float* vp = Vb + m * F0 + k;
                    fx4 v0 = *(const fx4*)(vp);
                    fx4 v1 = *(const fx4*)(vp + 4);
                    fx4 p0 = *(const fx4*)(sP + k);
                    fx4 p1 = *(const fx4*)(sP + k + 4);
                    #pragma unroll
                    for (int jj = 0; jj < 4; ++jj) {
                        w[jj]     = f2bf(lrelu(p0[jj] + v0[jj]));
                        w[4 + jj] = f2bf(lrelu(p1[jj] + v1[jj]));
                    }
                } else {
                    w = (u16x8){0, 0, 0, 0, 0, 0, 0, 0};
                }
                *(u16x8*)(sA0p + idx * 8) = w;
            }
        }
    }
    __syncthreads();

    const int mtB = wm ? 4 : 0, mtE = wm ? 7 : 4;
    const int c = ld & 15, rlo = (ld >> 4) * 4;
    const int a1off = (ld * 16) ^ (((ld >> 3) & 7) << 4);   // swz read offset

    // ---- edge layer 1: [112x96] @ [96x160] -> sA1p (swizzled packed-A) ----
    {
        const int nCnt = (wn < 2) ? 3 : 2;
        bf16x8 bw[3][3]; float bias[3];
        #pragma unroll
        for (int t = 0; t < 3; ++t) if (t < nCnt) {
            int nt = wn + 4 * t;
            bias[t] = feb1[16 * nt + c];
            #pragma unroll
            for (int kt = 0; kt < 3; ++kt)
                bw[t][kt] = fragGbl(W1p + (size_t)((kt * 10 + nt) * 64 + ld) * 8);
        }
        for (int mt = mtB; mt < mtE; ++mt) {
            bf16x8 a[3];
            #pragma unroll
            for (int kt = 0; kt < 3; ++kt)
                a[kt] = fragLds(sA0p + ((mt * 3 + kt) * 64 + ld) * 8);
            fx4 acc[3];
            #pragma unroll
            for (int t = 0; t < 3; ++t) acc[t] = (fx4){0.f, 0.f, 0.f, 0.f};
            #pragma unroll
            for (int kt = 0; kt < 3; ++kt)
                #pragma unroll
                for (int t = 0; t < 3; ++t)
                    if (t < nCnt) acc[t] = MFMA(a[kt], bw[t][kt], acc[t]);
            // swizzled quad-packed repack (HW-verified)
            #pragma unroll
            for (int t = 0; t < 3; ++t) if (t < nCnt) {
                int nt = wn + 4 * t;
                int f = 16 * nt + c;
                int lq = (f >> 3) & 3;
                int S  = (((rlo >> 3) + 2 * lq) & 7) << 4;
                char* base = (char*)sA1p + (mt * 5 + (nt >> 1)) * 1024 + (c & 4) * 2;
                #pragma unroll
                for (int r = 0; r < 4; ++r) {
                    u32 h = (u32)f2bf(lrelu(acc[t][r] + bias[t]));
                    u32x2 two = quadPack(h);
                    int rowl = rlo + 16 * lq + r;
                    if ((ld & 3) == 0)
                        *(u32x2*)(base + ((rowl * 16) ^ S)) = two;
                }
            }
        }
    }
    __syncthreads();

    // ---- edge layer 2 + fused aggregation over j (unchanged, verified) ----
    {
        bf16x8 bw[3][5]; float bias[3];
        float aggp[3] = {0.f, 0.f, 0.f};
        #pragma unroll
        for (int t = 0; t < 3; ++t) {
            int nt = wn + 4 * t;
            bias[t] = feb2[16 * nt + c];
            #pragma unroll
            for (int kt = 0; kt < 5; ++kt)
                bw[t][kt] = fragGbl(W2p + (size_t)((kt * 12 + nt) * 64 + ld) * 8);
        }
        for (int mt = mtB; mt < mtE; ++mt) {
            bf16x8 a[5];
            const char* rb = (const char*)sA1p + mt * 5120 + a1off;
            #pragma unroll
            for (int kt = 0; kt < 5; ++kt)
                a[kt] = fragLds((const u16*)(rb + kt * 1024));
            fx4 acc[3];
            #pragma unroll
            for (int t = 0; t < 3; ++t) acc[t] = (fx4){0.f, 0.f, 0.f, 0.f};
            #pragma unroll
            for (int kt = 0; kt < 5; ++kt)
                #pragma unroll
                for (int t = 0; t < 3; ++t)
                    acc[t] = MFMA(a[kt], bw[t][kt], acc[t]);
            // rows m = 16*mt + rlo + r ; mask out pad rows (>=100)
            bool ok = (mt < 6) || (rlo == 0);
            if (ok) {
                #pragma unroll
                for (int t = 0; t < 3; ++t)
                    #pragma unroll
                    for (int r = 0; r < 4; ++r)
                        aggp[t] += lrelu(acc[t][r] + bias[t]);
            }
        }
        #pragma unroll
        for (int t = 0; t < 3; ++t) {
            aggp[t] += __shfl_xor(aggp[t], 16, 64);
            aggp[t] += __shfl_xor(aggp[t], 32, 64);
        }
        if (ld < 16) {
            #pragma unroll
            for (int t = 0; t < 3; ++t)
                sAggP[wm * F2 + 16 * (wn + 4 * t) + ld] = aggp[t];
        }
    }
    __syncthreads();

    if (tid < F2) {
        float v = sAggP[tid] + sAggP[F2 + tid];
        agg[(size_t)row * F2 + tid] = f2bf(v);
    }
}

// ============================ node ============================
// EXACT r14 kernel (HW-verified: 400 blocks x 16 rows, non-edge 84->80us).
// 8 waves; waves own nt = wv and wv+8 (16 nt x 16 rows per layer).
// LDS 23.5KB. Layer-2 (N=32) on 2 waves. Same packed-weight layout as r10.
__global__ __launch_bounds__(512, 4) void node_kernel(
    const u16* __restrict__ agg, const float* __restrict__ x,
    const u16* __restrict__ n0p, const u16* __restrict__ n1p,
    const u16* __restrict__ n2p,
    const float* __restrict__ fnb0, const float* __restrict__ fnb1,
    const float* __restrict__ fnb2,
    float* __restrict__ out)
{
    const int blk = blockIdx.x;                 // 0..399, 16 rows each
    const int tid = threadIdx.x, ld = tid & 63, wv = tid >> 6;
    const int c = ld & 15, rlo = (ld >> 4) * 4;
    const int c0 = c & ~3;

    __shared__ __align__(16) u16 sH0p[7 * 512];   // 7168 B  [7kt][64][8]
    __shared__ __align__(16) u16 sH1p[8 * 512];   // 8192 B  [8kt2][64][8]
    __shared__ __align__(16) u16 sH2p[8 * 512];   // 8192 B

    // ---- stage H0 = [agg | x] packed-A for 16 rows (448 active threads) ----
    if (tid < 448) {
        int lane = tid & 63, kt = tid >> 6;       // kt < 7
        int k = 32 * kt + 8 * (lane >> 4);
        int m = lane & 15;
        int g = 16 * blk + m;
        u16x8 w;
        if (k < F2) {
            w = *(const u16x8*)(agg + (size_t)g * F2 + k);
        } else {
            const float* xp = x + (size_t)g * D_ + (k - F2);
            fx4 v0 = *(const fx4*)xp;
            fx4 v1 = *(const fx4*)(xp + 4);
            #pragma unroll
            for (int jj = 0; jj < 4; ++jj) {
                w[jj] = f2bf(v0[jj]); w[4 + jj] = f2bf(v1[jj]);
            }
        }
        *(u16x8*)(sH0p + tid * 8) = w;
    }
    __syncthreads();

    // ---- node layer 0: K=224 (7 kt), N=256 (nt = wv, wv+8), lrelu ----
    {
        fx4 acc[2];
        #pragma unroll
        for (int t = 0; t < 2; ++t) acc[t] = (fx4){0.f, 0.f, 0.f, 0.f};
        for (int kt = 0; kt < 7; ++kt) {
            bf16x8 a = fragLds(sH0p + (kt * 64 + ld) * 8);
            #pragma unroll
            for (int t = 0; t < 2; ++t) {
                int nt = wv + 8 * t;
                bf16x8 bw = fragGbl(n0p + (size_t)((kt * 16 + nt) * 64 + ld) * 8);
                acc[t] = MFMA(a, bw, acc[t]);
            }
        }
        #pragma unroll
        for (int t = 0; t < 2; ++t) {
            int f = 16 * (wv + 8 * t) + c;
            float bias = fnb0[f];
            int kt2 = f >> 5, lq = (f >> 3) & 3;
            u16* basep = sH1p + (kt2 * 64 + rlo + 16 * lq) * 8 + (c0 & 7);
            #pragma unroll
            for (int r = 0; r < 4; ++r) {
                u32 h = (u32)f2bf(lrelu(acc[t][r] + bias));
                u32x2 two = quadPack(h);
                if ((ld & 3) == 0)
                    *(u32x2*)(basep + r * 8) = two;
            }
        }
    }
    __syncthreads();

    // ---- node layer 1: K=256 (8 kt), N=256, lrelu ----
    {
        fx4 acc[2];
        #pragma unroll
        for (int t = 0; t < 2; ++t) acc[t] = (fx4){0.f, 0.f, 0.f, 0.f};
        for (int kt = 0; kt < 8; ++kt) {
            bf16x8 a = fragLds(sH1p + (kt * 64 + ld) * 8);
            #pragma unroll
            for (int t = 0; t < 2; ++t) {
                int nt = wv + 8 * t;
                bf16x8 bw = fragGbl(n1p + (size_t)((kt * 16 + nt) * 64 + ld) * 8);
                acc[t] = MFMA(a, bw, acc[t]);
            }
        }
        #pragma unroll
        for (int t = 0; t < 2; ++t) {
            int f = 16 * (wv + 8 * t) + c;
            float bias = fnb1[f];
            int kt2 = f >> 5, lq = (f >> 3) & 3;
            u16* basep = sH2p + (kt2 * 64 + rlo + 16 * lq) * 8 + (c0 & 7);
            #pragma unroll
            for (int r = 0; r < 4; ++r) {
                u32 h = (u32)f2bf(lrelu(acc[t][r] + bias));
                u32x2 two = quadPack(h);
                if ((ld & 3) == 0)
                    *(u32x2*)(basep + r * 8) = two;
            }
        }
    }
    __syncthreads();

    // ---- node layer 2: K=256 (8 kt), N=32 (2 nt), linear -> out ----
    if (wv < 2) {
        int nt = wv;
        fx4 acc = (fx4){0.f, 0.f, 0.f, 0.f};
        for (int kt = 0; kt < 8; ++kt) {
            bf16x8 a = fragLds(sH2p + (kt * 64 + ld) * 8);
            bf16x8 bw = fragGbl(n2p + (size_t)((kt * 2 + nt) * 64 + ld) * 8);
            acc = MFMA(a, bw, acc);
        }
        int f = 16 * nt + c;
        float bias = fnb2[f];
        #pragma unroll
        for (int r = 0; r < 4; ++r) {
            int g = 16 * blk + rlo + r;
            out[(size_t)g * FOUT + f] = acc[r] + bias;
        }
    }
}

extern "C" void kernel_launch(void* const* d_in, const int* in_sizes, int n_in,
                              void* d_out, int out_size, void* d_ws, size_t ws_size,
                              hipStream_t stream) {
    const float* x    = (const float*)d_in[0];
    const float* few0 = (const float*)d_in[1];
    const float* feb0 = (const float*)d_in[2];
    const float* few1 = (const float*)d_in[3];
    const float* feb1 = (const float*)d_in[4];
    const float* few2 = (const float*)d_in[5];
    const float* feb2 = (const float*)d_in[6];
    const float* fnw0 = (const float*)d_in[7];
    const float* fnb0 = (const float*)d_in[8];
    const float* fnw1 = (const float*)d_in[9];
    const float* fnb1 = (const float*)d_in[10];
    const float* fnw2 = (const float*)d_in[11];
    const float* fnb2 = (const float*)d_in[12];

    char* w = (char*)d_ws;
    float* P    = (float*)(w + OFF_P);
    float* V    = (float*)(w + OFF_V);
    u16*   aggb = (u16*)(w + OFF_AGG);
    u16*   pack = (u16*)(w + OFF_PACK);

    prep_kernel<<<PV_BLOCKS + PACK_BLOCKS, 512, 0, stream>>>(
        x, few0, feb0, few1, few2, fnw0, fnw1, fnw2, P, V, pack);

    edge_kernel<<<dim3(N_, B_), 512, 0, stream>>>(
        P, V, pack + PK_W1, pack + PK_W2, feb1, feb2, aggb);

    node_kernel<<<400, 512, 0, stream>>>(
        aggb, x, pack + PK_N0, pack + PK_N1, pack + PK_N2,
        fnb0, fnb1, fnb2, (float*)d_out);
}

// Round 16
// 239.098 us; speedup vs baseline: 1.1704x; 1.0243x over previous
//
#include <hip/hip_runtime.h>

#define B_    64
#define N_    100
#define D_    32
#define F0    96
#define F1    160
#define F2    192
#define HID   256
#define FOUT  32

typedef unsigned short u16;
typedef unsigned int   u32;
typedef u16   u16x8 __attribute__((ext_vector_type(8)));
typedef u32   u32x2 __attribute__((ext_vector_type(2)));
typedef __bf16 bf16x8 __attribute__((ext_vector_type(8)));
typedef float  fx4   __attribute__((ext_vector_type(4)));

// hardware RNE f32->bf16
__device__ __forceinline__ u16 f2bf(float f) {
    return __builtin_bit_cast(u16, (__bf16)f);
}
// lrelu(v) = max(v, 0.2v): exact (v>0 -> v; v<=0 -> 0.2v)
__device__ __forceinline__ float lrelu(float v) { return fmaxf(v, 0.2f * v); }

__device__ __forceinline__ bf16x8 fragLds(const u16* p) {
    return __builtin_bit_cast(bf16x8, *(const u16x8*)p);
}
__device__ __forceinline__ bf16x8 fragGbl(const u16* __restrict__ p) {
    return __builtin_bit_cast(bf16x8, *(const u16x8*)p);
}
#define MFMA(a, b, c) __builtin_amdgcn_mfma_f32_16x16x32_bf16((a), (b), (c), 0, 0, 0)

// quad-gather: lanes q..q+3 hold bf16 for 4 consecutive u16 of one fragment
// row; quad-lead ((ld&3)==0, even) stores 8B; even-lane pk is valid.
__device__ __forceinline__ u32x2 quadPack(u32 h) {
    u32 h1 = (u32)__shfl_xor((int)h, 1, 64);
    u32 pk = h | (h1 << 16);
    u32 pko = (u32)__shfl_xor((int)pk, 2, 64);
    return (u32x2){pk, pko};
}

// ---- ws layout (bytes) ---- (P region now unused; V kept at same offset)
#define OFF_P     0u
#define OFF_V     2457600u
#define OFF_AGG   4915200u
#define OFF_PACK  7372800u
#define PK_W1     0
#define PK_W2     15360
#define PK_N0     46080
#define PK_N1     103424
#define PK_N2     168960
#define PK_TOTAL  177152

#define PV_BLOCKS 1200         // V only: 6400*96 / 512 (P moved into edge)
#define PACK_BLOCKS 346

// ============================ prep ============================
__global__ __launch_bounds__(512) void prep_kernel(
    const float* __restrict__ x,
    const float* __restrict__ few0,
    const float* __restrict__ few1, const float* __restrict__ few2,
    const float* __restrict__ fnw0, const float* __restrict__ fnw1,
    const float* __restrict__ fnw2,
    float* __restrict__ V, u16* __restrict__ wpack)
{
    const int blk = blockIdx.x, tid = threadIdx.x;
    if (blk < PV_BLOCKS) {
        int o = blk * 512 + tid;           // < 6400*96
        int r = o / F0, k = o - r * F0;
        const float* xr = x + r * D_;
        float acc = 0.f;
        #pragma unroll
        for (int d = 0; d < D_; ++d) acc = fmaf(xr[d], few0[(D_ + d) * F0 + k], acc);
        V[r * F0 + k] = acc;
    } else {
        int p = (blk - PV_BLOCKS) * 512 + tid;
        const float* src; int start, Ncols, NT;
        if (p < PK_W2)      { start = PK_W1; src = few1; Ncols = F1;   NT = 10; }
        else if (p < PK_N0) { start = PK_W2; src = few2; Ncols = F2;   NT = 12; }
        else if (p < PK_N1) { start = PK_N0; src = fnw0; Ncols = HID;  NT = 16; }
        else if (p < PK_N2) { start = PK_N1; src = fnw1; Ncols = HID;  NT = 16; }
        else                { start = PK_N2; src = fnw2; Ncols = FOUT; NT = 2;  }
        int local = p - start;
        int j = local & 7, lane = (local >> 3) & 63, rest = local >> 9;
        int nt = rest % NT, kt = rest / NT;
        int n = 16 * nt + (lane & 15);
        int k = 32 * kt + 8 * (lane >> 4) + j;
        wpack[p] = f2bf(src[k * Ncols + n]);
    }
}

// ============================ edge ============================
// EXACT r10/r15 structure (HW-verified 160.7us: VGPR 52, zero spill, swizzled
// sA1p, 0 bank conflicts). ONLY change: sP is now COMPUTED in-block
// (feb0[h] + x[row]·few0[:,h], identical FMA order to old prep -> bit-exact)
// instead of loaded from the P workspace; prep's PV section halves.
// Occupancy is PINNED ~43% on this chip regardless of LDS (59/44/38/35KB all
// gave 43%) — unified VGPR+AGPR total caps waves/SIMD; do NOT chase occupancy
// (r5/r7/r8/r12/r13 all lost). L1 flat rebalance lost (r11: broke 3-chain acc
// ILP). In-register A0 lost (r12). sP removal lost (r14: +4.7us).
// Swizzle (HW-verified, 0 conflicts): write (rowl*16)^((((rlo>>3)+2*lq)&7)<<4),
// read (ld*16)^(((ld>>3)&7)<<4), within each 1024B kt2-block.
__global__ __launch_bounds__(512, 4) void edge_kernel(
    const float* __restrict__ x, const float* __restrict__ few0,
    const float* __restrict__ feb0, const float* __restrict__ V,
    const u16* __restrict__ W1p, const u16* __restrict__ W2p,
    const float* __restrict__ feb1, const float* __restrict__ feb2,
    u16* __restrict__ agg)
{
    const int i = blockIdx.x, b = blockIdx.y;
    const int tid = threadIdx.x, ld = tid & 63, wv = tid >> 6;
    const int wn = wv & 3, wm = wv >> 2;
    const int row = b * N_ + i;

    __shared__ __align__(16) u16  sA0p[7 * 3 * 512];   // 21504 B
    __shared__ __align__(16) u16  sA1p[7 * 5 * 512];   // 35840 B (swizzled)
    __shared__ __align__(16) float sP[F0];
    __shared__ __align__(16) float sAggP[2 * F2];      // [wm][f]

    // ---- compute P row in-block (bit-exact vs old prep: same FMA order) ----
    if (tid < F0) {
        const float* xr = x + (size_t)row * D_;
        float acc = feb0[tid];
        #pragma unroll
        for (int d = 0; d < D_; ++d) acc = fmaf(xr[d], few0[d * F0 + tid], acc);
        sP[tid] = acc;
    }
    __syncthreads();

    // ---- A0 packed build (vector, verified): pad rows -> 0 ----
    {
        const float* Vb = V + (size_t)b * N_ * F0;
        #pragma unroll
        for (int s = 0; s < 3; ++s) {
            int idx = tid + 512 * s;                   // < 1344 = 21*64
            if (idx < 1344) {
                int lane = idx & 63, rest = idx >> 6;  // rest < 21
                int kt = rest % 3, mt = rest / 3;
                int k = 32 * kt + 8 * (lane >> 4);
                int m = 16 * mt + (lane & 15);
                u16x8 w;
                if (m < N_) {
                    const float* vp = Vb + m * F0 + k;
                    fx4 v0 = *(const fx4*)(vp);
                    fx4 v1 = *(const fx4*)(vp + 4);
                    fx4 p0 = *(const fx4*)(sP + k);
                    fx4 p1 = *(const fx4*)(sP + k + 4);
                    #pragma unroll
                    for (int jj = 0; jj < 4; ++jj) {
                        w[jj]     = f2bf(lrelu(p0[jj] + v0[jj]));
                        w[4 + jj] = f2bf(lrelu(p1[jj] + v1[jj]));
                    }
                } else {
                    w = (u16x8){0, 0, 0, 0, 0, 0, 0, 0};
                }
                *(u16x8*)(sA0p + idx * 8) = w;
            }
        }
    }
    __syncthreads();

    const int mtB = wm ? 4 : 0, mtE = wm ? 7 : 4;
    const int c = ld & 15, rlo = (ld >> 4) * 4;
    const int a1off = (ld * 16) ^ (((ld >> 3) & 7) << 4);   // swz read offset

    // ---- edge layer 1: [112x96] @ [96x160] -> sA1p (swizzled packed-A) ----
    {
        const int nCnt = (wn < 2) ? 3 : 2;
        bf16x8 bw[3][3]; float bias[3];
        #pragma unroll
        for (int t = 0; t < 3; ++t) if (t < nCnt) {
            int nt = wn + 4 * t;
            bias[t] = feb1[16 * nt + c];
            #pragma unroll
            for (int kt = 0; kt < 3; ++kt)
                bw[t][kt] = fragGbl(W1p + (size_t)((kt * 10 + nt) * 64 + ld) * 8);
        }
        for (int mt = mtB; mt < mtE; ++mt) {
            bf16x8 a[3];
            #pragma unroll
            for (int kt = 0; kt < 3; ++kt)
                a[kt] = fragLds(sA0p + ((mt * 3 + kt) * 64 + ld) * 8);
            fx4 acc[3];
            #pragma unroll
            for (int t = 0; t < 3; ++t) acc[t] = (fx4){0.f, 0.f, 0.f, 0.f};
            #pragma unroll
            for (int kt = 0; kt < 3; ++kt)
                #pragma unroll
                for (int t = 0; t < 3; ++t)
                    if (t < nCnt) acc[t] = MFMA(a[kt], bw[t][kt], acc[t]);
            // swizzled quad-packed repack (HW-verified)
            #pragma unroll
            for (int t = 0; t < 3; ++t) if (t < nCnt) {
                int nt = wn + 4 * t;
                int f = 16 * nt + c;
                int lq = (f >> 3) & 3;
                int S  = (((rlo >> 3) + 2 * lq) & 7) << 4;
                char* base = (char*)sA1p + (mt * 5 + (nt >> 1)) * 1024 + (c & 4) * 2;
                #pragma unroll
                for (int r = 0; r < 4; ++r) {
                    u32 h = (u32)f2bf(lrelu(acc[t][r] + bias[t]));
                    u32x2 two = quadPack(h);
                    int rowl = rlo + 16 * lq + r;
                    if ((ld & 3) == 0)
                        *(u32x2*)(base + ((rowl * 16) ^ S)) = two;
                }
            }
        }
    }
    __syncthreads();

    // ---- edge layer 2 + fused aggregation over j (unchanged, verified) ----
    {
        bf16x8 bw[3][5]; float bias[3];
        float aggp[3] = {0.f, 0.f, 0.f};
        #pragma unroll
        for (int t = 0; t < 3; ++t) {
            int nt = wn + 4 * t;
            bias[t] = feb2[16 * nt + c];
            #pragma unroll
            for (int kt = 0; kt < 5; ++kt)
                bw[t][kt] = fragGbl(W2p + (size_t)((kt * 12 + nt) * 64 + ld) * 8);
        }
        for (int mt = mtB; mt < mtE; ++mt) {
            bf16x8 a[5];
            const char* rb = (const char*)sA1p + mt * 5120 + a1off;
            #pragma unroll
            for (int kt = 0; kt < 5; ++kt)
                a[kt] = fragLds((const u16*)(rb + kt * 1024));
            fx4 acc[3];
            #pragma unroll
            for (int t = 0; t < 3; ++t) acc[t] = (fx4){0.f, 0.f, 0.f, 0.f};
            #pragma unroll
            for (int kt = 0; kt < 5; ++kt)
                #pragma unroll
                for (int t = 0; t < 3; ++t)
                    acc[t] = MFMA(a[kt], bw[t][kt], acc[t]);
            // rows m = 16*mt + rlo + r ; mask out pad rows (>=100)
            bool ok = (mt < 6) || (rlo == 0);
            if (ok) {
                #pragma unroll
                for (int t = 0; t < 3; ++t)
                    #pragma unroll
                    for (int r = 0; r < 4; ++r)
                        aggp[t] += lrelu(acc[t][r] + bias[t]);
            }
        }
        #pragma unroll
        for (int t = 0; t < 3; ++t) {
            aggp[t] += __shfl_xor(aggp[t], 16, 64);
            aggp[t] += __shfl_xor(aggp[t], 32, 64);
        }
        if (ld < 16) {
            #pragma unroll
            for (int t = 0; t < 3; ++t)
                sAggP[wm * F2 + 16 * (wn + 4 * t) + ld] = aggp[t];
        }
    }
    __syncthreads();

    if (tid < F2) {
        float v = sAggP[tid] + sAggP[F2 + tid];
        agg[(size_t)row * F2 + tid] = f2bf(v);
    }
}

// ============================ node ============================
// EXACT r14/r15 kernel (HW-verified: 400 blocks x 16 rows).
// 8 waves; waves own nt = wv and wv+8 (16 nt x 16 rows per layer).
// LDS 23.5KB. Layer-2 (N=32) on 2 waves. Same packed-weight layout as r10.
__global__ __launch_bounds__(512, 4) void node_kernel(
    const u16* __restrict__ agg, const float* __restrict__ x,
    const u16* __restrict__ n0p, const u16* __restrict__ n1p,
    const u16* __restrict__ n2p,
    const float* __restrict__ fnb0, const float* __restrict__ fnb1,
    const float* __restrict__ fnb2,
    float* __restrict__ out)
{
    const int blk = blockIdx.x;                 // 0..399, 16 rows each
    const int tid = threadIdx.x, ld = tid & 63, wv = tid >> 6;
    const int c = ld & 15, rlo = (ld >> 4) * 4;
    const int c0 = c & ~3;

    __shared__ __align__(16) u16 sH0p[7 * 512];   // 7168 B  [7kt][64][8]
    __shared__ __align__(16) u16 sH1p[8 * 512];   // 8192 B  [8kt2][64][8]
    __shared__ __align__(16) u16 sH2p[8 * 512];   // 8192 B

    // ---- stage H0 = [agg | x] packed-A for 16 rows (448 active threads) ----
    if (tid < 448) {
        int lane = tid & 63, kt = tid >> 6;       // kt < 7
        int k = 32 * kt + 8 * (lane >> 4);
        int m = lane & 15;
        int g = 16 * blk + m;
        u16x8 w;
        if (k < F2) {
            w = *(const u16x8*)(agg + (size_t)g * F2 + k);
        } else {
            const float* xp = x + (size_t)g * D_ + (k - F2);
            fx4 v0 = *(const fx4*)xp;
            fx4 v1 = *(const fx4*)(xp + 4);
            #pragma unroll
            for (int jj = 0; jj < 4; ++jj) {
                w[jj] = f2bf(v0[jj]); w[4 + jj] = f2bf(v1[jj]);
            }
        }
        *(u16x8*)(sH0p + tid * 8) = w;
    }
    __syncthreads();

    // ---- node layer 0: K=224 (7 kt), N=256 (nt = wv, wv+8), lrelu ----
    {
        fx4 acc[2];
        #pragma unroll
        for (int t = 0; t < 2; ++t) acc[t] = (fx4){0.f, 0.f, 0.f, 0.f};
        for (int kt = 0; kt < 7; ++kt) {
            bf16x8 a = fragLds(sH0p + (kt * 64 + ld) * 8);
            #pragma unroll
            for (int t = 0; t < 2; ++t) {
                int nt = wv + 8 * t;
                bf16x8 bw = fragGbl(n0p + (size_t)((kt * 16 + nt) * 64 + ld) * 8);
                acc[t] = MFMA(a, bw, acc[t]);
            }
        }
        #pragma unroll
        for (int t = 0; t < 2; ++t) {
            int f = 16 * (wv + 8 * t) + c;
            float bias = fnb0[f];
            int kt2 = f >> 5, lq = (f >> 3) & 3;
            u16* basep = sH1p + (kt2 * 64 + rlo + 16 * lq) * 8 + (c0 & 7);
            #pragma unroll
            for (int r = 0; r < 4; ++r) {
                u32 h = (u32)f2bf(lrelu(acc[t][r] + bias));
                u32x2 two = quadPack(h);
                if ((ld & 3) == 0)
                    *(u32x2*)(basep + r * 8) = two;
            }
        }
    }
    __syncthreads();

    // ---- node layer 1: K=256 (8 kt), N=256, lrelu ----
    {
        fx4 acc[2];
        #pragma unroll
        for (int t = 0; t < 2; ++t) acc[t] = (fx4){0.f, 0.f, 0.f, 0.f};
        for (int kt = 0; kt < 8; ++kt) {
            bf16x8 a = fragLds(sH1p + (kt * 64 + ld) * 8);
            #pragma unroll
            for (int t = 0; t < 2; ++t) {
                int nt = wv + 8 * t;
                bf16x8 bw = fragGbl(n1p + (size_t)((kt * 16 + nt) * 64 + ld) * 8);
                acc[t] = MFMA(a, bw, acc[t]);
            }
        }
        #pragma unroll
        for (int t = 0; t < 2; ++t) {
            int f = 16 * (wv + 8 * t) + c;
            float bias = fnb1[f];
            int kt2 = f >> 5, lq = (f >> 3) & 3;
            u16* basep = sH2p + (kt2 * 64 + rlo + 16 * lq) * 8 + (c0 & 7);
            #pragma unroll
            for (int r = 0; r < 4; ++r) {
                u32 h = (u32)f2bf(lrelu(acc[t][r] + bias));
                u32x2 two = quadPack(h);
                if ((ld & 3) == 0)
                    *(u32x2*)(basep + r * 8) = two;
            }
        }
    }
    __syncthreads();

    // ---- node layer 2: K=256 (8 kt), N=32 (2 nt), linear -> out ----
    if (wv < 2) {
        int nt = wv;
        fx4 acc = (fx4){0.f, 0.f, 0.f, 0.f};
        for (int kt = 0; kt < 8; ++kt) {
            bf16x8 a = fragLds(sH2p + (kt * 64 + ld) * 8);
            bf16x8 bw = fragGbl(n2p + (size_t)((kt * 2 + nt) * 64 + ld) * 8);
            acc = MFMA(a, bw, acc);
        }
        int f = 16 * nt + c;
        float bias = fnb2[f];
        #pragma unroll
        for (int r = 0; r < 4; ++r) {
            int g = 16 * blk + rlo + r;
            out[(size_t)g * FOUT + f] = acc[r] + bias;
        }
    }
}

extern "C" void kernel_launch(void* const* d_in, const int* in_sizes, int n_in,
                              void* d_out, int out_size, void* d_ws, size_t ws_size,
                              hipStream_t stream) {
    const float* x    = (const float*)d_in[0];
    const float* few0 = (const float*)d_in[1];
    const float* feb0 = (const float*)d_in[2];
    const float* few1 = (const float*)d_in[3];
    const float* feb1 = (const float*)d_in[4];
    const float* few2 = (const float*)d_in[5];
    const float* feb2 = (const float*)d_in[6];
    const float* fnw0 = (const float*)d_in[7];
    const float* fnb0 = (const float*)d_in[8];
    const float* fnw1 = (const float*)d_in[9];
    const float* fnb1 = (const float*)d_in[10];
    const float* fnw2 = (const float*)d_in[11];
    const float* fnb2 = (const float*)d_in[12];

    char* w = (char*)d_ws;
    float* V    = (float*)(w + OFF_V);
    u16*   aggb = (u16*)(w + OFF_AGG);
    u16*   pack = (u16*)(w + OFF_PACK);

    prep_kernel<<<PV_BLOCKS + PACK_BLOCKS, 512, 0, stream>>>(
        x, few0, few1, few2, fnw0, fnw1, fnw2, V, pack);

    edge_kernel<<<dim3(N_, B_), 512, 0, stream>>>(
        x, few0, feb0, V, pack + PK_W1, pack + PK_W2, feb1, feb2, aggb);

    node_kernel<<<400, 512, 0, stream>>>(
        aggb, x, pack + PK_N0, pack + PK_N1, pack + PK_N2,
        fnb0, fnb1, fnb2, (float*)d_out);
}